// Round 5
// baseline (3521.713 us; speedup 1.0000x reference)
//
#include <hip/hip_runtime.h>
#include <hip/hip_bf16.h>

#define BATCH 2048
#define LSIG 2048
#define TSTEPS 512
#define CH 16            // LSTM steps per chunk
#define NCHUNK (TSTEPS / CH)
#define SS 4             // samples per block

typedef float v2f __attribute__((ext_vector_type(2)));
typedef float v4f __attribute__((ext_vector_type(4)));

__device__ __forceinline__ void pk_fma(v2f& d, v2f a, v2f b) {
    // d.x += a.x*b.x; d.y += a.y*b.y (VOP3P packed f32 FMA)
    asm("v_pk_fma_f32 %0, %1, %2, %0" : "+v"(d) : "v"(a), "v"(b));
}

__device__ __forceinline__ float sigf(float x) {
    return __fdividef(1.f, 1.f + __expf(-x));
}
__device__ __forceinline__ float tanhfast(float x) {
    return 1.f - __fdividef(2.f, __expf(2.f * x) + 1.f);
}

// 128 threads (2 waves) per (4 samples, branch).
// Phase A: conv1+relu+pool2 over a 34-row pooled window (4 samples).
// Phase B: conv2+relu+pool2, lane=(co,half), sliding 4-row register window.
// Phase C: LSTM; lane=(unit rg=tid>>2, k-quarter qid=tid&3). Each lane owns
//   all 4 gate rows {rg,32+rg,64+rg,96+rg} restricted to its 16-wide k-slice
//   (qid0/1: x[0:16],x[16:32]; qid2/3: h[0:16],h[16:32]) -> 64 weight VGPRs.
//   shfl_xor(1,2) quad-reduce; cell update redundant in-quad (c in regs);
//   double-buffered h in LDS -> ONE barrier per step, 4 samples amortized.
// All weights reloaded per chunk via asm-opaqued pointers (dead across other
// phases). Empirical launch_bounds model (R3/R4): VGPR cap = 512/(arg2 *
// waves_per_block) -> (128,2) = cap 128. Demand ~110 -> no spill.
__global__ __launch_bounds__(128, 2) void branch_kernel(
    const float* __restrict__ x0, const float* __restrict__ x1,
    const float* __restrict__ x2, const float* __restrict__ x3,
    const float* __restrict__ c1w, const float* __restrict__ c1b,
    const float* __restrict__ c2w, const float* __restrict__ c2b,
    const float* __restrict__ wih, const float* __restrict__ whh,
    const float* __restrict__ bih, const float* __restrict__ bhh,
    float* __restrict__ feats)
{
    const int s0   = blockIdx.x * SS;
    const int br   = blockIdx.y;
    const int tid  = threadIdx.x;
    const int lane = tid & 63;
    const int wave = tid >> 6;
    const int qid  = tid & 3;      // k-quarter
    const int rg   = tid >> 2;     // hidden unit 0..31
    const float* xg = (br == 0) ? x0 : (br == 1) ? x1 : (br == 2) ? x2 : x3;

    __shared__ float xs_c[SS][70];        // x window per chunk
    __shared__ float p1buf[SS][34][16];   // pooled1 window
    __shared__ float seqb[SS][CH][32];    // LSTM inputs for chunk
    __shared__ float hb[2][SS][32];       // double-buffered hidden state

    const int ci = tid & 15;              // conv1 out-channel
    const int co = lane & 31;             // conv2 out-channel
    const int hf = lane >> 5;             // conv2 input half

    // LSTM biases (resident, 4 regs)
    float bsv[4];
    #pragma unroll
    for (int g = 0; g < 4; ++g) {
        int r = g * 32 + rg;
        bsv[g] = bih[br * 128 + r] + bhh[br * 128 + r];
    }

    float cst[SS] = {0.f, 0.f, 0.f, 0.f};
    ((float*)hb)[tid] = 0.f;              // zero hb[0][*][*] (128 floats)

    #pragma unroll 1
    for (int chk = 0; chk < NCHUNK; ++chk) {
        const int tc0 = chk * CH;

        // ---- stage x window: xs_c[ss][i] = x[4*tc0 - 3 + i], i<70 ----
        #pragma unroll 1
        for (int it = 0; it < 3; ++it) {
            int idx = it * 128 + tid;
            if (idx < SS * 70) {
                int ssl = idx / 70, i = idx - ssl * 70;
                int g = 4 * tc0 - 3 + i;
                xs_c[ssl][i] = ((unsigned)g < (unsigned)LSIG)
                             ? xg[(size_t)(s0 + ssl) * LSIG + g] : 0.f;
            }
        }

        // ---- conv weights: reload per chunk (opaque => dead in phase C) ----
        const float* pc1 = c1w + br * 48 + ci * 3;  asm volatile("" : "+v"(pc1));
        const float w10 = pc1[0], w11 = pc1[1], w12 = pc1[2];
        const float* pb1 = c1b + br * 16 + ci;      asm volatile("" : "+v"(pb1));
        const float b1v = pb1[0];

        const float* pc2 = c2w + br * 1536 + co * 48 + hf * 24;
        asm volatile("" : "+v"(pc2));
        float wt[24];
        #pragma unroll
        for (int i = 0; i < 6; ++i) ((v4f*)wt)[i] = ((const v4f*)pc2)[i];
        v4f w2p[3][2];
        #pragma unroll
        for (int k = 0; k < 3; ++k)
            #pragma unroll
            for (int h2 = 0; h2 < 2; ++h2)
                w2p[k][h2] = (v4f){ wt[(h2 * 4 + 0) * 3 + k], wt[(h2 * 4 + 1) * 3 + k],
                                    wt[(h2 * 4 + 2) * 3 + k], wt[(h2 * 4 + 3) * 3 + k] };
        const float* pb2 = c2b + br * 32 + co;      asm volatile("" : "+v"(pb2));
        const float b2v = pb2[0];

        __syncthreads();

        // ---- phase A: 4 x 34 x 16 pooled1 window ----
        #pragma unroll 1
        for (int it = 0; it < 17; ++it) {
            int idx = it * 128 + tid;
            int rest = idx >> 4;
            int ssl = rest / 34, pl = rest - ssl * 34;
            float xa = xs_c[ssl][2 * pl + 0], xb = xs_c[ssl][2 * pl + 1];
            float xc = xs_c[ssl][2 * pl + 2], xd = xs_c[ssl][2 * pl + 3];
            float a0 = fmaf(xc, w12, fmaf(xb, w11, fmaf(xa, w10, b1v)));
            float a1 = fmaf(xd, w12, fmaf(xc, w11, fmaf(xb, w10, b1v)));
            float v = fmaxf(fmaxf(a0, a1), 0.f);
            int p1g = 2 * tc0 - 1 + pl;
            v = ((unsigned)p1g < (unsigned)(LSIG / 2)) ? v : 0.f;
            p1buf[ssl][pl][idx & 15] = v;
        }
        __syncthreads();

        // ---- phase B: conv2 + relu + pool2 -> seqb (sliding row window) ----
        #pragma unroll 1
        for (int sw = 0; sw < 2; ++sw) {
            const int ssl = wave * 2 + sw;
            const v4f* pbase = (const v4f*)&p1buf[ssl][0][0];  // 4 v4f per row
            const int h2o = hf * 2;
            v4f r0a = pbase[0 * 4 + h2o], r0b = pbase[0 * 4 + h2o + 1];
            v4f r1a = pbase[1 * 4 + h2o], r1b = pbase[1 * 4 + h2o + 1];
            v4f r2a = pbase[2 * 4 + h2o], r2b = pbase[2 * 4 + h2o + 1];
            v4f r3a = pbase[3 * 4 + h2o], r3b = pbase[3 * 4 + h2o + 1];
            #pragma unroll 1
            for (int tl = 0; tl < CH; ++tl) {
                v2f aA = {0.f, 0.f}, aB = {0.f, 0.f};
                pk_fma(aA, r0a.xy, w2p[0][0].xy); pk_fma(aA, r0a.zw, w2p[0][0].zw);
                pk_fma(aA, r0b.xy, w2p[0][1].xy); pk_fma(aA, r0b.zw, w2p[0][1].zw);
                pk_fma(aA, r1a.xy, w2p[1][0].xy); pk_fma(aA, r1a.zw, w2p[1][0].zw);
                pk_fma(aA, r1b.xy, w2p[1][1].xy); pk_fma(aA, r1b.zw, w2p[1][1].zw);
                pk_fma(aA, r2a.xy, w2p[2][0].xy); pk_fma(aA, r2a.zw, w2p[2][0].zw);
                pk_fma(aA, r2b.xy, w2p[2][1].xy); pk_fma(aA, r2b.zw, w2p[2][1].zw);
                pk_fma(aB, r1a.xy, w2p[0][0].xy); pk_fma(aB, r1a.zw, w2p[0][0].zw);
                pk_fma(aB, r1b.xy, w2p[0][1].xy); pk_fma(aB, r1b.zw, w2p[0][1].zw);
                pk_fma(aB, r2a.xy, w2p[1][0].xy); pk_fma(aB, r2a.zw, w2p[1][0].zw);
                pk_fma(aB, r2b.xy, w2p[1][1].xy); pk_fma(aB, r2b.zw, w2p[1][1].zw);
                pk_fma(aB, r3a.xy, w2p[2][0].xy); pk_fma(aB, r3a.zw, w2p[2][0].zw);
                pk_fma(aB, r3b.xy, w2p[2][1].xy); pk_fma(aB, r3b.zw, w2p[2][1].zw);
                float sA = aA.x + aA.y, sB = aB.x + aB.y;
                sA += __shfl_xor(sA, 32);
                sB += __shfl_xor(sB, 32);
                if (hf == 0)
                    seqb[ssl][tl][co] = fmaxf(fmaxf(sA, sB) + b2v, 0.f);
                r0a = r2a; r0b = r2b; r1a = r3a; r1b = r3b;
                if (tl < CH - 1) {
                    r2a = pbase[(2 * tl + 4) * 4 + h2o]; r2b = pbase[(2 * tl + 4) * 4 + h2o + 1];
                    r3a = pbase[(2 * tl + 5) * 4 + h2o]; r3b = pbase[(2 * tl + 5) * 4 + h2o + 1];
                }
            }
        }

        // ---- LSTM weights: reload per chunk (16 x v4f, opaque) ----
        const float* wsrc = (qid < 2 ? wih : whh) + (size_t)br * 4096 + (qid & 1) * 16;
        asm volatile("" : "+v"(wsrc));
        v4f wq[4][4];
        #pragma unroll
        for (int g = 0; g < 4; ++g) {
            const v4f* wp = (const v4f*)(wsrc + (g * 32 + rg) * 32);
            #pragma unroll
            for (int j = 0; j < 4; ++j) wq[g][j] = wp[j];
        }

        // ---- phase C: LSTM, one barrier per step ----
        #pragma unroll 1
        for (int tl = 0; tl < CH; ++tl) {
            __syncthreads();
            const int p = (tc0 + tl) & 1;
            #pragma unroll
            for (int ssl = 0; ssl < SS; ++ssl) {
                const v4f* src = (qid < 2) ? (const v4f*)&seqb[ssl][tl][0]
                                           : (const v4f*)&hb[p][ssl][0];
                const v4f* sp = src + (qid & 1) * 4;
                v2f ac0 = {0.f, 0.f}, ac1 = {0.f, 0.f}, ac2 = {0.f, 0.f}, ac3 = {0.f, 0.f};
                #pragma unroll
                for (int j = 0; j < 4; ++j) {
                    v4f xv = sp[j];
                    pk_fma(ac0, xv.xy, wq[0][j].xy); pk_fma(ac0, xv.zw, wq[0][j].zw);
                    pk_fma(ac1, xv.xy, wq[1][j].xy); pk_fma(ac1, xv.zw, wq[1][j].zw);
                    pk_fma(ac2, xv.xy, wq[2][j].xy); pk_fma(ac2, xv.zw, wq[2][j].zw);
                    pk_fma(ac3, xv.xy, wq[3][j].xy); pk_fma(ac3, xv.zw, wq[3][j].zw);
                }
                float si = ac0.x + ac0.y;
                float sf = ac1.x + ac1.y;
                float sg = ac2.x + ac2.y;
                float so = ac3.x + ac3.y;
                si += __shfl_xor(si, 1); si += __shfl_xor(si, 2);
                sf += __shfl_xor(sf, 1); sf += __shfl_xor(sf, 2);
                sg += __shfl_xor(sg, 1); sg += __shfl_xor(sg, 2);
                so += __shfl_xor(so, 1); so += __shfl_xor(so, 2);
                si = sigf(si + bsv[0]);
                sf = sigf(sf + bsv[1]);
                sg = tanhfast(sg + bsv[2]);
                so = sigf(so + bsv[3]);
                float c = fmaf(sf, cst[ssl], si * sg);
                cst[ssl] = c;
                float h = so * tanhfast(c);
                if (qid == 0) hb[p ^ 1][ssl][rg] = h;
            }
        }
    }

    __syncthreads();
    // last step (t=511) wrote parity (511&1)^1 = 0
    feats[((size_t)br * BATCH + s0 + (tid >> 5)) * 32 + (tid & 31)] =
        hb[0][tid >> 5][tid & 31];
}

// ---------------- tail: bottleneck + 8-qubit statevector + classifier -------

__device__ __forceinline__ void apply1q(float2* psi, int lane, int q,
                                        float2 g00, float2 g01,
                                        float2 g10, float2 g11)
{
    const int shift = 7 - q;
    const int right = 1 << shift;
    #pragma unroll
    for (int pp = 0; pp < 2; ++pp) {
        int p  = lane + 64 * pp;
        int l  = p >> shift;
        int r  = p & (right - 1);
        int i0 = (l << (shift + 1)) + r;
        int i1 = i0 + right;
        float2 a = psi[i0], b = psi[i1];
        float2 n0 = make_float2(g00.x * a.x - g00.y * a.y + g01.x * b.x - g01.y * b.y,
                                g00.x * a.y + g00.y * a.x + g01.x * b.y + g01.y * b.x);
        float2 n1 = make_float2(g10.x * a.x - g10.y * a.y + g11.x * b.x - g11.y * b.y,
                                g10.x * a.y + g10.y * a.x + g11.x * b.y + g11.y * b.x);
        psi[i0] = n0;
        psi[i1] = n1;
    }
    __syncthreads();
}

__global__ __launch_bounds__(64) void tail_kernel(
    const float* __restrict__ feats, const float* __restrict__ bw,
    const float* __restrict__ bb, const float* __restrict__ qw,
    const float* __restrict__ cw, const float* __restrict__ cb,
    float* __restrict__ out)
{
    const int s    = blockIdx.x;
    const int lane = threadIdx.x;

    __shared__ float comb[128];
    __shared__ float2 psi[256];
    __shared__ float ang[8];

    comb[lane]      = feats[(size_t)(lane >> 5) * (BATCH * 32) + (size_t)s * 32 + (lane & 31)];
    comb[lane + 64] = feats[(size_t)((lane + 64) >> 5) * (BATCH * 32) + (size_t)s * 32 + (lane & 31)];
    __syncthreads();

    {
        int q = lane >> 3, k0 = lane & 7;
        float p = 0.f;
        #pragma unroll
        for (int i = 0; i < 16; ++i) {
            int k = k0 + 8 * i;
            p = fmaf(comb[k], bw[q * 128 + k], p);
        }
        p += __shfl_xor(p, 4);
        p += __shfl_xor(p, 2);
        p += __shfl_xor(p, 1);
        if (k0 == 0) ang[q] = tanhf(p + bb[q]);
    }
    #pragma unroll
    for (int r = 0; r < 4; ++r) {
        int idx = lane + 64 * r;
        psi[idx] = make_float2(idx == 0 ? 1.f : 0.f, 0.f);
    }
    __syncthreads();

    const float PI_F = 3.14159265358979323846f;

    for (int q = 0; q < 8; ++q) {
        float half = ang[q] * PI_F * 0.5f;
        float cv = cosf(half), sv = sinf(half);
        apply1q(psi, lane, q,
                make_float2(cv, 0.f), make_float2(0.f, -sv),
                make_float2(0.f, -sv), make_float2(cv, 0.f));
    }

    for (int l = 0; l < 3; ++l) {
        for (int q = 0; q < 8; ++q) {
            float phi = qw[(l * 8 + q) * 3 + 0];
            float th  = qw[(l * 8 + q) * 3 + 1];
            float om  = qw[(l * 8 + q) * 3 + 2];
            float ct = cosf(0.5f * th), st = sinf(0.5f * th);
            float A = 0.5f * (phi + om), D = 0.5f * (phi - om);
            float cA = cosf(A), sA = sinf(A), cD = cosf(D), sD = sinf(D);
            apply1q(psi, lane, q,
                    make_float2(ct * cA, -ct * sA), make_float2(-st * cD, -st * sD),
                    make_float2(st * cD, -st * sD), make_float2(ct * cA,  ct * sA));
        }
        int stride = l + 1;
        for (int q = 0; q + stride < 8; ++q) {
            int cbit = 1 << (7 - q);
            int tbit = 1 << (7 - (q + stride));
            #pragma unroll
            for (int r = 0; r < 4; ++r) {
                int idx = lane + 64 * r;
                if ((idx & cbit) && !(idx & tbit)) {
                    int j = idx | tbit;
                    float2 tmp = psi[idx];
                    psi[idx] = psi[j];
                    psi[j] = tmp;
                }
            }
            __syncthreads();
        }
    }

    float z[8];
    #pragma unroll
    for (int q = 0; q < 8; ++q) z[q] = 0.f;
    #pragma unroll
    for (int r = 0; r < 4; ++r) {
        int idx = lane + 64 * r;
        float2 a = psi[idx];
        float pr = a.x * a.x + a.y * a.y;
        #pragma unroll
        for (int q = 0; q < 8; ++q)
            z[q] += (idx & (1 << (7 - q))) ? -pr : pr;
    }
    #pragma unroll
    for (int q = 0; q < 8; ++q) {
        #pragma unroll
        for (int off = 32; off; off >>= 1) z[q] += __shfl_xor(z[q], off);
    }
    if (lane == 0) {
        #pragma unroll
        for (int c = 0; c < 3; ++c) {
            float acc = cb[c];
            #pragma unroll
            for (int q = 0; q < 8; ++q) acc = fmaf(z[q], cw[c * 8 + q], acc);
            out[s * 3 + c] = acc;
        }
    }
}

extern "C" void kernel_launch(void* const* d_in, const int* in_sizes, int n_in,
                              void* d_out, int out_size, void* d_ws, size_t ws_size,
                              hipStream_t stream)
{
    (void)in_sizes; (void)n_in; (void)out_size; (void)ws_size;
    const float* x0  = (const float*)d_in[0];
    const float* x1  = (const float*)d_in[1];
    const float* x2  = (const float*)d_in[2];
    const float* x3  = (const float*)d_in[3];
    const float* c1w = (const float*)d_in[4];
    const float* c1b = (const float*)d_in[5];
    const float* c2w = (const float*)d_in[6];
    const float* c2b = (const float*)d_in[7];
    const float* wih = (const float*)d_in[8];
    const float* whh = (const float*)d_in[9];
    const float* bih = (const float*)d_in[10];
    const float* bhh = (const float*)d_in[11];
    const float* bw  = (const float*)d_in[12];
    const float* bb  = (const float*)d_in[13];
    const float* qw  = (const float*)d_in[14];
    const float* cw  = (const float*)d_in[15];
    const float* cb  = (const float*)d_in[16];

    float* feats = (float*)d_ws;  // [4][BATCH][32] f32 = 1 MB

    branch_kernel<<<dim3(BATCH / SS, 4), 128, 0, stream>>>(
        x0, x1, x2, x3, c1w, c1b, c2w, c2b, wih, whh, bih, bhh, feats);
    tail_kernel<<<BATCH, 64, 0, stream>>>(
        feats, bw, bb, qw, cw, cb, (float*)d_out);
}

// Round 6
// 2809.506 us; speedup vs baseline: 1.2535x; 1.2535x over previous
//
#include <hip/hip_runtime.h>
#include <hip/hip_bf16.h>

#define BATCH 2048
#define LSIG 2048
#define TSTEPS 512
#define CH 16            // LSTM steps per chunk
#define NCHUNK (TSTEPS / CH)

typedef float v2f __attribute__((ext_vector_type(2)));
typedef float v4f __attribute__((ext_vector_type(4)));

__device__ __forceinline__ void pk_fma(v2f& d, v2f a, v2f b) {
    // d.x += a.x*b.x; d.y += a.y*b.y (VOP3P packed f32 FMA)
    asm("v_pk_fma_f32 %0, %1, %2, %0" : "+v"(d) : "v"(a), "v"(b));
}

__device__ __forceinline__ float sigf(float x) {
    return __fdividef(1.f, 1.f + __expf(-x));
}
__device__ __forceinline__ float tanhfast(float x) {
    return 1.f - __fdividef(2.f, __expf(2.f * x) + 1.f);
}

// One 64-lane wave per (sample, branch). R2 dataflow, restructured registers:
//  A : conv1+relu+pool2 -> p1buf[34][16]
//  B : conv2+relu+pool2 -> seqb[16][32]  (lane=(co,hf), pk_fma, shfl combine)
//  B': x-part of LSTM gates for the whole chunk: gpx[16]x2 in REGISTERS
//      (Wih rows lane,lane+64 chunk-reloaded via opaque ptr -> 64 regs)
//  C : recurrent h-part only: 32 pk_fma/step (Whh 64 regs), R2's minimal-
//      transcendental activations, double-buffered h in LDS.
// No phase needs >~120 VGPRs -> launch_bounds(64,4) caps at 128, no spill
// (R2 spilled at 176 demand; R3 hit the 168->256 granule cliff; R5 bloated
// VALU with quad-redundant transcendentals).
__global__ __launch_bounds__(64, 4) void branch_kernel(
    const float* __restrict__ x0, const float* __restrict__ x1,
    const float* __restrict__ x2, const float* __restrict__ x3,
    const float* __restrict__ c1w, const float* __restrict__ c1b,
    const float* __restrict__ c2w, const float* __restrict__ c2b,
    const float* __restrict__ wih, const float* __restrict__ whh,
    const float* __restrict__ bih, const float* __restrict__ bhh,
    float* __restrict__ feats)
{
    const int s    = blockIdx.x;
    const int br   = blockIdx.y;
    const int lane = threadIdx.x;
    const float* xg = (br == 0) ? x0 : (br == 1) ? x1 : (br == 2) ? x2 : x3;

    __shared__ float xs_c[70];        // x window for one chunk
    __shared__ float p1buf[34][16];   // pooled1 window
    __shared__ float seqb[CH][32];    // conv2 outputs = LSTM inputs
    __shared__ float hb[2][32];       // double-buffered hidden state

    const int ci = lane & 15;         // conv1 out-channel
    const int co = lane & 31;         // conv2 out-channel
    const int hf = lane >> 5;         // conv2 input-channel half

    // LSTM biases for gate rows lane (i/f) and lane+64 (g/o)
    const float bs0 = bih[br * 128 + lane]      + bhh[br * 128 + lane];
    const float bs1 = bih[br * 128 + lane + 64] + bhh[br * 128 + lane + 64];

    if (lane < 32) hb[0][lane] = 0.f;
    float c_state = 0.f;

    #pragma unroll 1
    for (int chk = 0; chk < NCHUNK; ++chk) {
        const int tc0 = chk * CH;

        // ---- stage x window: xs_c[i] = x[4*tc0 - 3 + i], i<70 ----
        {
            int g = 4 * tc0 - 3 + lane;
            xs_c[lane] = ((unsigned)g < (unsigned)LSIG) ? xg[(size_t)s * LSIG + g] : 0.f;
            if (lane < 6) {
                int g2 = 4 * tc0 + 61 + lane;
                xs_c[64 + lane] = ((unsigned)g2 < (unsigned)LSIG) ? xg[(size_t)s * LSIG + g2] : 0.f;
            }
        }

        // ---- conv weights: reload per chunk via opaque pointers ----
        const float* pc1 = c1w + br * 48 + ci * 3;  asm volatile("" : "+v"(pc1));
        const float w10 = pc1[0], w11 = pc1[1], w12 = pc1[2];
        const float* pb1 = c1b + br * 16 + ci;      asm volatile("" : "+v"(pb1));
        const float b1v = pb1[0];

        const float* pc2 = c2w + br * 1536 + co * 48 + hf * 24;
        asm volatile("" : "+v"(pc2));
        float wt[24];
        #pragma unroll
        for (int i = 0; i < 6; ++i) ((v4f*)wt)[i] = ((const v4f*)pc2)[i];
        v4f w2p[3][2];
        #pragma unroll
        for (int k = 0; k < 3; ++k)
            #pragma unroll
            for (int h2 = 0; h2 < 2; ++h2)
                w2p[k][h2] = (v4f){ wt[(h2 * 4 + 0) * 3 + k], wt[(h2 * 4 + 1) * 3 + k],
                                    wt[(h2 * 4 + 2) * 3 + k], wt[(h2 * 4 + 3) * 3 + k] };
        const float* pb2 = c2b + br * 32 + co;      asm volatile("" : "+v"(pb2));
        const float b2v = pb2[0];

        __syncthreads();

        // ---- phase A: 34 x 16 pooled1 window ----
        #pragma unroll 1
        for (int it = 0; it < 9; ++it) {
            int idx = it * 64 + lane;
            if (idx < 34 * 16) {
                int pl = idx >> 4;
                float xa = xs_c[2 * pl + 0], xb = xs_c[2 * pl + 1];
                float xc = xs_c[2 * pl + 2], xd = xs_c[2 * pl + 3];
                float a0 = fmaf(xc, w12, fmaf(xb, w11, fmaf(xa, w10, b1v)));
                float a1 = fmaf(xd, w12, fmaf(xc, w11, fmaf(xb, w10, b1v)));
                float v = fmaxf(fmaxf(a0, a1), 0.f);
                int p1g = 2 * tc0 - 1 + pl;
                v = ((unsigned)p1g < (unsigned)(LSIG / 2)) ? v : 0.f;
                p1buf[pl][idx & 15] = v;
            }
        }
        __syncthreads();

        // ---- phase B: conv2 + relu + pool2 -> seqb (sliding row window) ----
        {
            const v4f* pbase = (const v4f*)&p1buf[0][0];   // 4 v4f per row
            const int h2o = hf * 2;
            v4f r0a = pbase[0 * 4 + h2o], r0b = pbase[0 * 4 + h2o + 1];
            v4f r1a = pbase[1 * 4 + h2o], r1b = pbase[1 * 4 + h2o + 1];
            v4f r2a = pbase[2 * 4 + h2o], r2b = pbase[2 * 4 + h2o + 1];
            v4f r3a = pbase[3 * 4 + h2o], r3b = pbase[3 * 4 + h2o + 1];
            #pragma unroll 1
            for (int tl = 0; tl < CH; ++tl) {
                v2f aA = {0.f, 0.f}, aB = {0.f, 0.f};
                pk_fma(aA, r0a.xy, w2p[0][0].xy); pk_fma(aA, r0a.zw, w2p[0][0].zw);
                pk_fma(aA, r0b.xy, w2p[0][1].xy); pk_fma(aA, r0b.zw, w2p[0][1].zw);
                pk_fma(aA, r1a.xy, w2p[1][0].xy); pk_fma(aA, r1a.zw, w2p[1][0].zw);
                pk_fma(aA, r1b.xy, w2p[1][1].xy); pk_fma(aA, r1b.zw, w2p[1][1].zw);
                pk_fma(aA, r2a.xy, w2p[2][0].xy); pk_fma(aA, r2a.zw, w2p[2][0].zw);
                pk_fma(aA, r2b.xy, w2p[2][1].xy); pk_fma(aA, r2b.zw, w2p[2][1].zw);
                pk_fma(aB, r1a.xy, w2p[0][0].xy); pk_fma(aB, r1a.zw, w2p[0][0].zw);
                pk_fma(aB, r1b.xy, w2p[0][1].xy); pk_fma(aB, r1b.zw, w2p[0][1].zw);
                pk_fma(aB, r2a.xy, w2p[1][0].xy); pk_fma(aB, r2a.zw, w2p[1][0].zw);
                pk_fma(aB, r2b.xy, w2p[1][1].xy); pk_fma(aB, r2b.zw, w2p[1][1].zw);
                pk_fma(aB, r3a.xy, w2p[2][0].xy); pk_fma(aB, r3a.zw, w2p[2][0].zw);
                pk_fma(aB, r3b.xy, w2p[2][1].xy); pk_fma(aB, r3b.zw, w2p[2][1].zw);
                float sA = aA.x + aA.y, sB = aB.x + aB.y;
                sA += __shfl_xor(sA, 32);
                sB += __shfl_xor(sB, 32);
                if (hf == 0)
                    seqb[tl][co] = fmaxf(fmaxf(sA, sB) + b2v, 0.f);
                r0a = r2a; r0b = r2b; r1a = r3a; r1b = r3b;
                if (tl < CH - 1) {
                    r2a = pbase[(2 * tl + 4) * 4 + h2o]; r2b = pbase[(2 * tl + 4) * 4 + h2o + 1];
                    r3a = pbase[(2 * tl + 5) * 4 + h2o]; r3b = pbase[(2 * tl + 5) * 4 + h2o + 1];
                }
            }
        }
        __syncthreads();

        // ---- phase B': x-part of gates for the whole chunk -> registers ----
        float gpx0[CH], gpx1[CH];
        {
            const float* pwi = wih + (size_t)br * 4096 + (size_t)lane * 32;
            asm volatile("" : "+v"(pwi));
            v4f wiA[8], wiB[8];
            #pragma unroll
            for (int j = 0; j < 8; ++j) {
                wiA[j] = ((const v4f*)pwi)[j];
                wiB[j] = ((const v4f*)(pwi + 64 * 32))[j];
            }
            #pragma unroll
            for (int tl = 0; tl < CH; ++tl) {
                const v4f* xq = (const v4f*)&seqb[tl][0];
                v2f aA = {0.f, 0.f}, aB = {0.f, 0.f};
                #pragma unroll
                for (int j = 0; j < 8; ++j) {
                    v4f xv = xq[j];
                    pk_fma(aA, xv.xy, wiA[j].xy); pk_fma(aA, xv.zw, wiA[j].zw);
                    pk_fma(aB, xv.xy, wiB[j].xy); pk_fma(aB, xv.zw, wiB[j].zw);
                }
                gpx0[tl] = aA.x + aA.y;
                gpx1[tl] = aB.x + aB.y;
            }
        }

        // ---- phase C: recurrent h-part, one barrier per step ----
        {
            const float* pwh = whh + (size_t)br * 4096 + (size_t)lane * 32;
            asm volatile("" : "+v"(pwh));
            v4f whA[8], whB[8];
            #pragma unroll
            for (int j = 0; j < 8; ++j) {
                whA[j] = ((const v4f*)pwh)[j];
                whB[j] = ((const v4f*)(pwh + 64 * 32))[j];
            }
            #pragma unroll
            for (int tl = 0; tl < CH; ++tl) {
                __syncthreads();
                const int p = (tc0 + tl) & 1;
                const v4f* hq = (const v4f*)&hb[p][0];
                v2f aA = {0.f, 0.f}, aB = {0.f, 0.f};
                #pragma unroll
                for (int j = 0; j < 8; ++j) {
                    v4f hv = hq[j];
                    pk_fma(aA, hv.xy, whA[j].xy); pk_fma(aA, hv.zw, whA[j].zw);
                    pk_fma(aB, hv.xy, whB[j].xy); pk_fma(aB, hv.zw, whB[j].zw);
                }
                float g0 = bs0 + gpx0[tl] + aA.x + aA.y;  // i (lane<32) / f
                float g1 = bs1 + gpx1[tl] + aB.x + aB.y;  // g (lane<32) / o
                float a0 = sigf(g0);
                // tanh(g1) for lanes<32, sigmoid(g1) for lanes>=32 (shared exp)
                float earg = (lane < 32) ? 2.f * g1 : -g1;
                float e1 = __expf(fminf(earg, 80.f));
                float num = (lane < 32) ? e1 - 1.f : 1.f;
                float a1 = __fdividef(num, e1 + 1.f);
                float fa = __shfl_xor(a0, 32);   // sig(f_m) for lanes<32
                float oa = __shfl_xor(a1, 32);   // sig(o_m) for lanes<32
                if (lane < 32) {
                    c_state = fmaf(fa, c_state, a0 * a1);
                    hb[p ^ 1][lane] = oa * tanhfast(c_state);
                }
            }
        }
    }

    __syncthreads();
    // last step (t=511) wrote parity (511&1)^1 = 0
    if (lane < 32)
        feats[((size_t)br * BATCH + s) * 32 + lane] = hb[0][lane];
}

// ---------------- tail: bottleneck + 8-qubit statevector + classifier -------

__device__ __forceinline__ void apply1q(float2* psi, int lane, int q,
                                        float2 g00, float2 g01,
                                        float2 g10, float2 g11)
{
    const int shift = 7 - q;
    const int right = 1 << shift;
    #pragma unroll
    for (int pp = 0; pp < 2; ++pp) {
        int p  = lane + 64 * pp;
        int l  = p >> shift;
        int r  = p & (right - 1);
        int i0 = (l << (shift + 1)) + r;
        int i1 = i0 + right;
        float2 a = psi[i0], b = psi[i1];
        float2 n0 = make_float2(g00.x * a.x - g00.y * a.y + g01.x * b.x - g01.y * b.y,
                                g00.x * a.y + g00.y * a.x + g01.x * b.y + g01.y * b.x);
        float2 n1 = make_float2(g10.x * a.x - g10.y * a.y + g11.x * b.x - g11.y * b.y,
                                g10.x * a.y + g10.y * a.x + g11.x * b.y + g11.y * b.x);
        psi[i0] = n0;
        psi[i1] = n1;
    }
    __syncthreads();
}

__global__ __launch_bounds__(64) void tail_kernel(
    const float* __restrict__ feats, const float* __restrict__ bw,
    const float* __restrict__ bb, const float* __restrict__ qw,
    const float* __restrict__ cw, const float* __restrict__ cb,
    float* __restrict__ out)
{
    const int s    = blockIdx.x;
    const int lane = threadIdx.x;

    __shared__ float comb[128];
    __shared__ float2 psi[256];
    __shared__ float ang[8];

    comb[lane]      = feats[(size_t)(lane >> 5) * (BATCH * 32) + (size_t)s * 32 + (lane & 31)];
    comb[lane + 64] = feats[(size_t)((lane + 64) >> 5) * (BATCH * 32) + (size_t)s * 32 + (lane & 31)];
    __syncthreads();

    {
        int q = lane >> 3, k0 = lane & 7;
        float p = 0.f;
        #pragma unroll
        for (int i = 0; i < 16; ++i) {
            int k = k0 + 8 * i;
            p = fmaf(comb[k], bw[q * 128 + k], p);
        }
        p += __shfl_xor(p, 4);
        p += __shfl_xor(p, 2);
        p += __shfl_xor(p, 1);
        if (k0 == 0) ang[q] = tanhf(p + bb[q]);
    }
    #pragma unroll
    for (int r = 0; r < 4; ++r) {
        int idx = lane + 64 * r;
        psi[idx] = make_float2(idx == 0 ? 1.f : 0.f, 0.f);
    }
    __syncthreads();

    const float PI_F = 3.14159265358979323846f;

    for (int q = 0; q < 8; ++q) {
        float half = ang[q] * PI_F * 0.5f;
        float cv = cosf(half), sv = sinf(half);
        apply1q(psi, lane, q,
                make_float2(cv, 0.f), make_float2(0.f, -sv),
                make_float2(0.f, -sv), make_float2(cv, 0.f));
    }

    for (int l = 0; l < 3; ++l) {
        for (int q = 0; q < 8; ++q) {
            float phi = qw[(l * 8 + q) * 3 + 0];
            float th  = qw[(l * 8 + q) * 3 + 1];
            float om  = qw[(l * 8 + q) * 3 + 2];
            float ct = cosf(0.5f * th), st = sinf(0.5f * th);
            float A = 0.5f * (phi + om), D = 0.5f * (phi - om);
            float cA = cosf(A), sA = sinf(A), cD = cosf(D), sD = sinf(D);
            apply1q(psi, lane, q,
                    make_float2(ct * cA, -ct * sA), make_float2(-st * cD, -st * sD),
                    make_float2(st * cD, -st * sD), make_float2(ct * cA,  ct * sA));
        }
        int stride = l + 1;
        for (int q = 0; q + stride < 8; ++q) {
            int cbit = 1 << (7 - q);
            int tbit = 1 << (7 - (q + stride));
            #pragma unroll
            for (int r = 0; r < 4; ++r) {
                int idx = lane + 64 * r;
                if ((idx & cbit) && !(idx & tbit)) {
                    int j = idx | tbit;
                    float2 tmp = psi[idx];
                    psi[idx] = psi[j];
                    psi[j] = tmp;
                }
            }
            __syncthreads();
        }
    }

    float z[8];
    #pragma unroll
    for (int q = 0; q < 8; ++q) z[q] = 0.f;
    #pragma unroll
    for (int r = 0; r < 4; ++r) {
        int idx = lane + 64 * r;
        float2 a = psi[idx];
        float pr = a.x * a.x + a.y * a.y;
        #pragma unroll
        for (int q = 0; q < 8; ++q)
            z[q] += (idx & (1 << (7 - q))) ? -pr : pr;
    }
    #pragma unroll
    for (int q = 0; q < 8; ++q) {
        #pragma unroll
        for (int off = 32; off; off >>= 1) z[q] += __shfl_xor(z[q], off);
    }
    if (lane == 0) {
        #pragma unroll
        for (int c = 0; c < 3; ++c) {
            float acc = cb[c];
            #pragma unroll
            for (int q = 0; q < 8; ++q) acc = fmaf(z[q], cw[c * 8 + q], acc);
            out[s * 3 + c] = acc;
        }
    }
}

extern "C" void kernel_launch(void* const* d_in, const int* in_sizes, int n_in,
                              void* d_out, int out_size, void* d_ws, size_t ws_size,
                              hipStream_t stream)
{
    (void)in_sizes; (void)n_in; (void)out_size; (void)ws_size;
    const float* x0  = (const float*)d_in[0];
    const float* x1  = (const float*)d_in[1];
    const float* x2  = (const float*)d_in[2];
    const float* x3  = (const float*)d_in[3];
    const float* c1w = (const float*)d_in[4];
    const float* c1b = (const float*)d_in[5];
    const float* c2w = (const float*)d_in[6];
    const float* c2b = (const float*)d_in[7];
    const float* wih = (const float*)d_in[8];
    const float* whh = (const float*)d_in[9];
    const float* bih = (const float*)d_in[10];
    const float* bhh = (const float*)d_in[11];
    const float* bw  = (const float*)d_in[12];
    const float* bb  = (const float*)d_in[13];
    const float* qw  = (const float*)d_in[14];
    const float* cw  = (const float*)d_in[15];
    const float* cb  = (const float*)d_in[16];

    float* feats = (float*)d_ws;  // [4][BATCH][32] f32 = 1 MB

    branch_kernel<<<dim3(BATCH, 4), 64, 0, stream>>>(
        x0, x1, x2, x3, c1w, c1b, c2w, c2b, wih, whh, bih, bhh, feats);
    tail_kernel<<<BATCH, 64, 0, stream>>>(
        feats, bw, bb, qw, cw, cb, (float*)d_out);
}

// Round 7
// 2204.208 us; speedup vs baseline: 1.5977x; 1.2746x over previous
//
#include <hip/hip_runtime.h>
#include <hip/hip_bf16.h>

#define BATCH 2048
#define LSIG 2048
#define TSTEPS 512
#define CH 16            // LSTM steps per chunk
#define NCHUNK (TSTEPS / CH)

typedef float v2f __attribute__((ext_vector_type(2)));
typedef float v4f __attribute__((ext_vector_type(4)));

__device__ __forceinline__ void pk_fma(v2f& d, v2f a, v2f b) {
    // d.x += a.x*b.x; d.y += a.y*b.y (VOP3P packed f32 FMA)
    asm("v_pk_fma_f32 %0, %1, %2, %0" : "+v"(d) : "v"(a), "v"(b));
}

__device__ __forceinline__ float sigf(float x) {
    return __fdividef(1.f, 1.f + __expf(-x));
}
__device__ __forceinline__ float tanhfast(float x) {
    return 1.f - __fdividef(2.f, __expf(2.f * x) + 1.f);
}

// One 64-lane wave per (sample, branch). R6 dataflow, fixed register cap:
//  A : conv1+relu+pool2 -> p1buf[34][16]
//  B : conv2+relu+pool2 -> seqb[16][32]  (lane=(co,hf), pk_fma, shfl combine)
//  B': x-part of LSTM gates for the whole chunk: gpx[16]x2 in REGISTERS
//      (Wih rows lane,lane+64 chunk-reloaded via opaque ptr -> 64 regs)
//  C : recurrent h-part only: 32 pk_fma/step (Whh 64 regs), minimal-
//      transcendental activations, double-buffered h in LDS. Single-wave
//      block => __syncthreads is just an lgkmcnt wait (cheap).
// EMPIRICAL launch_bounds model (R2-R6): VGPR cap = 512/(2*arg2), regardless
// of block size. arg2=4 -> cap 64 (R6: spilled 1.5GB). arg2=2 -> cap 128 >=
// demand ~115 -> spill-free, still 4 waves/SIMD.
__global__ __launch_bounds__(64, 2) void branch_kernel(
    const float* __restrict__ x0, const float* __restrict__ x1,
    const float* __restrict__ x2, const float* __restrict__ x3,
    const float* __restrict__ c1w, const float* __restrict__ c1b,
    const float* __restrict__ c2w, const float* __restrict__ c2b,
    const float* __restrict__ wih, const float* __restrict__ whh,
    const float* __restrict__ bih, const float* __restrict__ bhh,
    float* __restrict__ feats)
{
    const int s    = blockIdx.x;
    const int br   = blockIdx.y;
    const int lane = threadIdx.x;
    const float* xg = (br == 0) ? x0 : (br == 1) ? x1 : (br == 2) ? x2 : x3;

    __shared__ float xs_c[70];        // x window for one chunk
    __shared__ float p1buf[34][16];   // pooled1 window
    __shared__ float seqb[CH][32];    // conv2 outputs = LSTM inputs
    __shared__ float hb[2][32];       // double-buffered hidden state

    const int ci = lane & 15;         // conv1 out-channel
    const int co = lane & 31;         // conv2 out-channel
    const int hf = lane >> 5;         // conv2 input-channel half

    // LSTM biases for gate rows lane (i/f) and lane+64 (g/o)
    const float bs0 = bih[br * 128 + lane]      + bhh[br * 128 + lane];
    const float bs1 = bih[br * 128 + lane + 64] + bhh[br * 128 + lane + 64];

    if (lane < 32) hb[0][lane] = 0.f;
    float c_state = 0.f;

    #pragma unroll 1
    for (int chk = 0; chk < NCHUNK; ++chk) {
        const int tc0 = chk * CH;

        // ---- stage x window: xs_c[i] = x[4*tc0 - 3 + i], i<70 ----
        {
            int g = 4 * tc0 - 3 + lane;
            xs_c[lane] = ((unsigned)g < (unsigned)LSIG) ? xg[(size_t)s * LSIG + g] : 0.f;
            if (lane < 6) {
                int g2 = 4 * tc0 + 61 + lane;
                xs_c[64 + lane] = ((unsigned)g2 < (unsigned)LSIG) ? xg[(size_t)s * LSIG + g2] : 0.f;
            }
        }

        // ---- conv weights: reload per chunk via opaque pointers ----
        const float* pc1 = c1w + br * 48 + ci * 3;  asm volatile("" : "+v"(pc1));
        const float w10 = pc1[0], w11 = pc1[1], w12 = pc1[2];
        const float* pb1 = c1b + br * 16 + ci;      asm volatile("" : "+v"(pb1));
        const float b1v = pb1[0];

        const float* pc2 = c2w + br * 1536 + co * 48 + hf * 24;
        asm volatile("" : "+v"(pc2));
        float wt[24];
        #pragma unroll
        for (int i = 0; i < 6; ++i) ((v4f*)wt)[i] = ((const v4f*)pc2)[i];
        v4f w2p[3][2];
        #pragma unroll
        for (int k = 0; k < 3; ++k)
            #pragma unroll
            for (int h2 = 0; h2 < 2; ++h2)
                w2p[k][h2] = (v4f){ wt[(h2 * 4 + 0) * 3 + k], wt[(h2 * 4 + 1) * 3 + k],
                                    wt[(h2 * 4 + 2) * 3 + k], wt[(h2 * 4 + 3) * 3 + k] };
        const float* pb2 = c2b + br * 32 + co;      asm volatile("" : "+v"(pb2));
        const float b2v = pb2[0];

        __syncthreads();

        // ---- phase A: 34 x 16 pooled1 window ----
        #pragma unroll 1
        for (int it = 0; it < 9; ++it) {
            int idx = it * 64 + lane;
            if (idx < 34 * 16) {
                int pl = idx >> 4;
                float xa = xs_c[2 * pl + 0], xb = xs_c[2 * pl + 1];
                float xc = xs_c[2 * pl + 2], xd = xs_c[2 * pl + 3];
                float a0 = fmaf(xc, w12, fmaf(xb, w11, fmaf(xa, w10, b1v)));
                float a1 = fmaf(xd, w12, fmaf(xc, w11, fmaf(xb, w10, b1v)));
                float v = fmaxf(fmaxf(a0, a1), 0.f);
                int p1g = 2 * tc0 - 1 + pl;
                v = ((unsigned)p1g < (unsigned)(LSIG / 2)) ? v : 0.f;
                p1buf[pl][idx & 15] = v;
            }
        }
        __syncthreads();

        // ---- phase B: conv2 + relu + pool2 -> seqb (sliding row window) ----
        {
            const v4f* pbase = (const v4f*)&p1buf[0][0];   // 4 v4f per row
            const int h2o = hf * 2;
            v4f r0a = pbase[0 * 4 + h2o], r0b = pbase[0 * 4 + h2o + 1];
            v4f r1a = pbase[1 * 4 + h2o], r1b = pbase[1 * 4 + h2o + 1];
            v4f r2a = pbase[2 * 4 + h2o], r2b = pbase[2 * 4 + h2o + 1];
            v4f r3a = pbase[3 * 4 + h2o], r3b = pbase[3 * 4 + h2o + 1];
            #pragma unroll 1
            for (int tl = 0; tl < CH; ++tl) {
                v2f aA = {0.f, 0.f}, aB = {0.f, 0.f};
                pk_fma(aA, r0a.xy, w2p[0][0].xy); pk_fma(aA, r0a.zw, w2p[0][0].zw);
                pk_fma(aA, r0b.xy, w2p[0][1].xy); pk_fma(aA, r0b.zw, w2p[0][1].zw);
                pk_fma(aA, r1a.xy, w2p[1][0].xy); pk_fma(aA, r1a.zw, w2p[1][0].zw);
                pk_fma(aA, r1b.xy, w2p[1][1].xy); pk_fma(aA, r1b.zw, w2p[1][1].zw);
                pk_fma(aA, r2a.xy, w2p[2][0].xy); pk_fma(aA, r2a.zw, w2p[2][0].zw);
                pk_fma(aA, r2b.xy, w2p[2][1].xy); pk_fma(aA, r2b.zw, w2p[2][1].zw);
                pk_fma(aB, r1a.xy, w2p[0][0].xy); pk_fma(aB, r1a.zw, w2p[0][0].zw);
                pk_fma(aB, r1b.xy, w2p[0][1].xy); pk_fma(aB, r1b.zw, w2p[0][1].zw);
                pk_fma(aB, r2a.xy, w2p[1][0].xy); pk_fma(aB, r2a.zw, w2p[1][0].zw);
                pk_fma(aB, r2b.xy, w2p[1][1].xy); pk_fma(aB, r2b.zw, w2p[1][1].zw);
                pk_fma(aB, r3a.xy, w2p[2][0].xy); pk_fma(aB, r3a.zw, w2p[2][0].zw);
                pk_fma(aB, r3b.xy, w2p[2][1].xy); pk_fma(aB, r3b.zw, w2p[2][1].zw);
                float sA = aA.x + aA.y, sB = aB.x + aB.y;
                sA += __shfl_xor(sA, 32);
                sB += __shfl_xor(sB, 32);
                if (hf == 0)
                    seqb[tl][co] = fmaxf(fmaxf(sA, sB) + b2v, 0.f);
                r0a = r2a; r0b = r2b; r1a = r3a; r1b = r3b;
                if (tl < CH - 1) {
                    r2a = pbase[(2 * tl + 4) * 4 + h2o]; r2b = pbase[(2 * tl + 4) * 4 + h2o + 1];
                    r3a = pbase[(2 * tl + 5) * 4 + h2o]; r3b = pbase[(2 * tl + 5) * 4 + h2o + 1];
                }
            }
        }
        __syncthreads();

        // ---- phase B': x-part of gates for the whole chunk -> registers ----
        float gpx0[CH], gpx1[CH];
        {
            const float* pwi = wih + (size_t)br * 4096 + (size_t)lane * 32;
            asm volatile("" : "+v"(pwi));
            v4f wiA[8], wiB[8];
            #pragma unroll
            for (int j = 0; j < 8; ++j) {
                wiA[j] = ((const v4f*)pwi)[j];
                wiB[j] = ((const v4f*)(pwi + 64 * 32))[j];
            }
            #pragma unroll
            for (int tl = 0; tl < CH; ++tl) {
                const v4f* xq = (const v4f*)&seqb[tl][0];
                v2f aA = {0.f, 0.f}, aB = {0.f, 0.f};
                #pragma unroll
                for (int j = 0; j < 8; ++j) {
                    v4f xv = xq[j];
                    pk_fma(aA, xv.xy, wiA[j].xy); pk_fma(aA, xv.zw, wiA[j].zw);
                    pk_fma(aB, xv.xy, wiB[j].xy); pk_fma(aB, xv.zw, wiB[j].zw);
                }
                gpx0[tl] = aA.x + aA.y;
                gpx1[tl] = aB.x + aB.y;
            }
        }

        // ---- phase C: recurrent h-part, one (cheap) barrier per step ----
        {
            const float* pwh = whh + (size_t)br * 4096 + (size_t)lane * 32;
            asm volatile("" : "+v"(pwh));
            v4f whA[8], whB[8];
            #pragma unroll
            for (int j = 0; j < 8; ++j) {
                whA[j] = ((const v4f*)pwh)[j];
                whB[j] = ((const v4f*)(pwh + 64 * 32))[j];
            }
            #pragma unroll
            for (int tl = 0; tl < CH; ++tl) {
                __syncthreads();
                const int p = (tc0 + tl) & 1;
                const v4f* hq = (const v4f*)&hb[p][0];
                v2f aA = {0.f, 0.f}, aB = {0.f, 0.f};
                #pragma unroll
                for (int j = 0; j < 8; ++j) {
                    v4f hv = hq[j];
                    pk_fma(aA, hv.xy, whA[j].xy); pk_fma(aA, hv.zw, whA[j].zw);
                    pk_fma(aB, hv.xy, whB[j].xy); pk_fma(aB, hv.zw, whB[j].zw);
                }
                float g0 = bs0 + gpx0[tl] + aA.x + aA.y;  // i (lane<32) / f
                float g1 = bs1 + gpx1[tl] + aB.x + aB.y;  // g (lane<32) / o
                float a0 = sigf(g0);
                // tanh(g1) for lanes<32, sigmoid(g1) for lanes>=32 (shared exp)
                float earg = (lane < 32) ? 2.f * g1 : -g1;
                float e1 = __expf(fminf(earg, 80.f));
                float num = (lane < 32) ? e1 - 1.f : 1.f;
                float a1 = __fdividef(num, e1 + 1.f);
                float fa = __shfl_xor(a0, 32);   // sig(f_m) for lanes<32
                float oa = __shfl_xor(a1, 32);   // sig(o_m) for lanes<32
                if (lane < 32) {
                    c_state = fmaf(fa, c_state, a0 * a1);
                    hb[p ^ 1][lane] = oa * tanhfast(c_state);
                }
            }
        }
    }

    __syncthreads();
    // last step (t=511) wrote parity (511&1)^1 = 0
    if (lane < 32)
        feats[((size_t)br * BATCH + s) * 32 + lane] = hb[0][lane];
}

// ---------------- tail: bottleneck + 8-qubit statevector + classifier -------

__device__ __forceinline__ void apply1q(float2* psi, int lane, int q,
                                        float2 g00, float2 g01,
                                        float2 g10, float2 g11)
{
    const int shift = 7 - q;
    const int right = 1 << shift;
    #pragma unroll
    for (int pp = 0; pp < 2; ++pp) {
        int p  = lane + 64 * pp;
        int l  = p >> shift;
        int r  = p & (right - 1);
        int i0 = (l << (shift + 1)) + r;
        int i1 = i0 + right;
        float2 a = psi[i0], b = psi[i1];
        float2 n0 = make_float2(g00.x * a.x - g00.y * a.y + g01.x * b.x - g01.y * b.y,
                                g00.x * a.y + g00.y * a.x + g01.x * b.y + g01.y * b.x);
        float2 n1 = make_float2(g10.x * a.x - g10.y * a.y + g11.x * b.x - g11.y * b.y,
                                g10.x * a.y + g10.y * a.x + g11.x * b.y + g11.y * b.x);
        psi[i0] = n0;
        psi[i1] = n1;
    }
    __syncthreads();
}

__global__ __launch_bounds__(64) void tail_kernel(
    const float* __restrict__ feats, const float* __restrict__ bw,
    const float* __restrict__ bb, const float* __restrict__ qw,
    const float* __restrict__ cw, const float* __restrict__ cb,
    float* __restrict__ out)
{
    const int s    = blockIdx.x;
    const int lane = threadIdx.x;

    __shared__ float comb[128];
    __shared__ float2 psi[256];
    __shared__ float ang[8];

    comb[lane]      = feats[(size_t)(lane >> 5) * (BATCH * 32) + (size_t)s * 32 + (lane & 31)];
    comb[lane + 64] = feats[(size_t)((lane + 64) >> 5) * (BATCH * 32) + (size_t)s * 32 + (lane & 31)];
    __syncthreads();

    {
        int q = lane >> 3, k0 = lane & 7;
        float p = 0.f;
        #pragma unroll
        for (int i = 0; i < 16; ++i) {
            int k = k0 + 8 * i;
            p = fmaf(comb[k], bw[q * 128 + k], p);
        }
        p += __shfl_xor(p, 4);
        p += __shfl_xor(p, 2);
        p += __shfl_xor(p, 1);
        if (k0 == 0) ang[q] = tanhf(p + bb[q]);
    }
    #pragma unroll
    for (int r = 0; r < 4; ++r) {
        int idx = lane + 64 * r;
        psi[idx] = make_float2(idx == 0 ? 1.f : 0.f, 0.f);
    }
    __syncthreads();

    const float PI_F = 3.14159265358979323846f;

    for (int q = 0; q < 8; ++q) {
        float half = ang[q] * PI_F * 0.5f;
        float cv = cosf(half), sv = sinf(half);
        apply1q(psi, lane, q,
                make_float2(cv, 0.f), make_float2(0.f, -sv),
                make_float2(0.f, -sv), make_float2(cv, 0.f));
    }

    for (int l = 0; l < 3; ++l) {
        for (int q = 0; q < 8; ++q) {
            float phi = qw[(l * 8 + q) * 3 + 0];
            float th  = qw[(l * 8 + q) * 3 + 1];
            float om  = qw[(l * 8 + q) * 3 + 2];
            float ct = cosf(0.5f * th), st = sinf(0.5f * th);
            float A = 0.5f * (phi + om), D = 0.5f * (phi - om);
            float cA = cosf(A), sA = sinf(A), cD = cosf(D), sD = sinf(D);
            apply1q(psi, lane, q,
                    make_float2(ct * cA, -ct * sA), make_float2(-st * cD, -st * sD),
                    make_float2(st * cD, -st * sD), make_float2(ct * cA,  ct * sA));
        }
        int stride = l + 1;
        for (int q = 0; q + stride < 8; ++q) {
            int cbit = 1 << (7 - q);
            int tbit = 1 << (7 - (q + stride));
            #pragma unroll
            for (int r = 0; r < 4; ++r) {
                int idx = lane + 64 * r;
                if ((idx & cbit) && !(idx & tbit)) {
                    int j = idx | tbit;
                    float2 tmp = psi[idx];
                    psi[idx] = psi[j];
                    psi[j] = tmp;
                }
            }
            __syncthreads();
        }
    }

    float z[8];
    #pragma unroll
    for (int q = 0; q < 8; ++q) z[q] = 0.f;
    #pragma unroll
    for (int r = 0; r < 4; ++r) {
        int idx = lane + 64 * r;
        float2 a = psi[idx];
        float pr = a.x * a.x + a.y * a.y;
        #pragma unroll
        for (int q = 0; q < 8; ++q)
            z[q] += (idx & (1 << (7 - q))) ? -pr : pr;
    }
    #pragma unroll
    for (int q = 0; q < 8; ++q) {
        #pragma unroll
        for (int off = 32; off; off >>= 1) z[q] += __shfl_xor(z[q], off);
    }
    if (lane == 0) {
        #pragma unroll
        for (int c = 0; c < 3; ++c) {
            float acc = cb[c];
            #pragma unroll
            for (int q = 0; q < 8; ++q) acc = fmaf(z[q], cw[c * 8 + q], acc);
            out[s * 3 + c] = acc;
        }
    }
}

extern "C" void kernel_launch(void* const* d_in, const int* in_sizes, int n_in,
                              void* d_out, int out_size, void* d_ws, size_t ws_size,
                              hipStream_t stream)
{
    (void)in_sizes; (void)n_in; (void)out_size; (void)ws_size;
    const float* x0  = (const float*)d_in[0];
    const float* x1  = (const float*)d_in[1];
    const float* x2  = (const float*)d_in[2];
    const float* x3  = (const float*)d_in[3];
    const float* c1w = (const float*)d_in[4];
    const float* c1b = (const float*)d_in[5];
    const float* c2w = (const float*)d_in[6];
    const float* c2b = (const float*)d_in[7];
    const float* wih = (const float*)d_in[8];
    const float* whh = (const float*)d_in[9];
    const float* bih = (const float*)d_in[10];
    const float* bhh = (const float*)d_in[11];
    const float* bw  = (const float*)d_in[12];
    const float* bb  = (const float*)d_in[13];
    const float* qw  = (const float*)d_in[14];
    const float* cw  = (const float*)d_in[15];
    const float* cb  = (const float*)d_in[16];

    float* feats = (float*)d_ws;  // [4][BATCH][32] f32 = 1 MB

    branch_kernel<<<dim3(BATCH, 4), 64, 0, stream>>>(
        x0, x1, x2, x3, c1w, c1b, c2w, c2b, wih, whh, bih, bhh, feats);
    tail_kernel<<<BATCH, 64, 0, stream>>>(
        feats, bw, bb, qw, cw, cb, (float*)d_out);
}

// Round 8
// 2188.802 us; speedup vs baseline: 1.6090x; 1.0070x over previous
//
#include <hip/hip_runtime.h>
#include <hip/hip_bf16.h>

#define BATCH 2048
#define LSIG 2048
#define TSTEPS 512
#define CH 8             // LSTM steps per chunk
#define NCHUNK (TSTEPS / CH)
#define SPB 2            // samples per block (one wave)

typedef float v2f __attribute__((ext_vector_type(2)));
typedef float v4f __attribute__((ext_vector_type(4)));

__device__ __forceinline__ void pk_fma(v2f& d, v2f a, v2f b) {
    // d.x += a.x*b.x; d.y += a.y*b.y (VOP3P packed f32 FMA)
    asm("v_pk_fma_f32 %0, %1, %2, %0" : "+v"(d) : "v"(a), "v"(b));
}

__device__ __forceinline__ float sigf(float x) {
    return __fdividef(1.f, 1.f + __expf(-x));
}
__device__ __forceinline__ float tanhfast(float x) {
    return 1.f - __fdividef(2.f, __expf(2.f * x) + 1.f);
}

// One 64-lane wave per (2 samples, branch). R7 dataflow + 2 independent
// sample-streams per wave for latency hiding in the recurrent phase:
//  per chunk (CH=8): for ss in {0,1}: stage x, A (conv1+pool), B (conv2+pool
//  -> seqb[ss]); then B' (x-part of gates, both ss -> 32 gpx regs); then C
//  (h-part, both ss interleaved per step -> 2 independent dep-chains hide
//  each other's LDS/exp latency; weights shared in 64 regs).
// EMPIRICAL model (R2-R7): VGPR budget = 256/arg2; occupancy ~= arg2 w/EU.
// arg2=2 -> budget 128 >= peak demand ~121 -> no spill.
__global__ __launch_bounds__(64, 2) void branch_kernel(
    const float* __restrict__ x0, const float* __restrict__ x1,
    const float* __restrict__ x2, const float* __restrict__ x3,
    const float* __restrict__ c1w, const float* __restrict__ c1b,
    const float* __restrict__ c2w, const float* __restrict__ c2b,
    const float* __restrict__ wih, const float* __restrict__ whh,
    const float* __restrict__ bih, const float* __restrict__ bhh,
    float* __restrict__ feats)
{
    const int s0   = blockIdx.x * SPB;
    const int br   = blockIdx.y;
    const int lane = threadIdx.x;
    const float* xg = (br == 0) ? x0 : (br == 1) ? x1 : (br == 2) ? x2 : x3;

    __shared__ float xs_c[4 * CH + 6];        // x window (38)
    __shared__ float p1buf[2 * CH + 2][16];   // pooled1 window (18 rows)
    __shared__ float seqb[SPB][CH][32];       // conv2 outputs = LSTM inputs
    __shared__ float hb[2][SPB][32];          // double-buffered hidden state

    const int ci = lane & 15;         // conv1 out-channel
    const int co = lane & 31;         // conv2 out-channel
    const int hf = lane >> 5;         // conv2 input-channel half

    // LSTM biases for gate rows lane (i/f) and lane+64 (g/o)
    const float bs0 = bih[br * 128 + lane]      + bhh[br * 128 + lane];
    const float bs1 = bih[br * 128 + lane + 64] + bhh[br * 128 + lane + 64];

    hb[0][lane >> 5][lane & 31] = 0.f;        // zero hb[0][ss][*]
    float cst0 = 0.f, cst1 = 0.f;

    #pragma unroll 1
    for (int chk = 0; chk < NCHUNK; ++chk) {
        const int tc0 = chk * CH;

        // ---- conv weights: reload per chunk via opaque pointers ----
        const float* pc1 = c1w + br * 48 + ci * 3;  asm volatile("" : "+v"(pc1));
        const float w10 = pc1[0], w11 = pc1[1], w12 = pc1[2];
        const float* pb1 = c1b + br * 16 + ci;      asm volatile("" : "+v"(pb1));
        const float b1v = pb1[0];

        const float* pc2 = c2w + br * 1536 + co * 48 + hf * 24;
        asm volatile("" : "+v"(pc2));
        float wt[24];
        #pragma unroll
        for (int i = 0; i < 6; ++i) ((v4f*)wt)[i] = ((const v4f*)pc2)[i];
        v4f w2p[3][2];
        #pragma unroll
        for (int k = 0; k < 3; ++k)
            #pragma unroll
            for (int h2 = 0; h2 < 2; ++h2)
                w2p[k][h2] = (v4f){ wt[(h2 * 4 + 0) * 3 + k], wt[(h2 * 4 + 1) * 3 + k],
                                    wt[(h2 * 4 + 2) * 3 + k], wt[(h2 * 4 + 3) * 3 + k] };
        const float* pb2 = c2b + br * 32 + co;      asm volatile("" : "+v"(pb2));
        const float b2v = pb2[0];

        // ---- per-sample front-end: stage -> A -> B ----
        #pragma unroll 1
        for (int ss = 0; ss < SPB; ++ss) {
            __syncthreads();   // protect xs/p1buf/seqb from previous users
            if (lane < 4 * CH + 6) {
                int g = 4 * tc0 - 3 + lane;
                xs_c[lane] = ((unsigned)g < (unsigned)LSIG)
                           ? xg[(size_t)(s0 + ss) * LSIG + g] : 0.f;
            }
            __syncthreads();

            // phase A: (2CH+2) x 16 pooled1 window
            #pragma unroll
            for (int it = 0; it < 5; ++it) {
                int idx = it * 64 + lane;
                if (idx < (2 * CH + 2) * 16) {
                    int pl = idx >> 4;
                    float xa = xs_c[2 * pl + 0], xb = xs_c[2 * pl + 1];
                    float xc = xs_c[2 * pl + 2], xd = xs_c[2 * pl + 3];
                    float a0 = fmaf(xc, w12, fmaf(xb, w11, fmaf(xa, w10, b1v)));
                    float a1 = fmaf(xd, w12, fmaf(xc, w11, fmaf(xb, w10, b1v)));
                    float v = fmaxf(fmaxf(a0, a1), 0.f);
                    int p1g = 2 * tc0 - 1 + pl;
                    v = ((unsigned)p1g < (unsigned)(LSIG / 2)) ? v : 0.f;
                    p1buf[pl][idx & 15] = v;
                }
            }
            __syncthreads();

            // phase B: conv2 + relu + pool2 -> seqb[ss] (sliding row window)
            {
                const v4f* pbase = (const v4f*)&p1buf[0][0];   // 4 v4f per row
                const int h2o = hf * 2;
                v4f r0a = pbase[0 * 4 + h2o], r0b = pbase[0 * 4 + h2o + 1];
                v4f r1a = pbase[1 * 4 + h2o], r1b = pbase[1 * 4 + h2o + 1];
                v4f r2a = pbase[2 * 4 + h2o], r2b = pbase[2 * 4 + h2o + 1];
                v4f r3a = pbase[3 * 4 + h2o], r3b = pbase[3 * 4 + h2o + 1];
                #pragma unroll 1
                for (int tl = 0; tl < CH; ++tl) {
                    v2f aA = {0.f, 0.f}, aB = {0.f, 0.f};
                    pk_fma(aA, r0a.xy, w2p[0][0].xy); pk_fma(aA, r0a.zw, w2p[0][0].zw);
                    pk_fma(aA, r0b.xy, w2p[0][1].xy); pk_fma(aA, r0b.zw, w2p[0][1].zw);
                    pk_fma(aA, r1a.xy, w2p[1][0].xy); pk_fma(aA, r1a.zw, w2p[1][0].zw);
                    pk_fma(aA, r1b.xy, w2p[1][1].xy); pk_fma(aA, r1b.zw, w2p[1][1].zw);
                    pk_fma(aA, r2a.xy, w2p[2][0].xy); pk_fma(aA, r2a.zw, w2p[2][0].zw);
                    pk_fma(aA, r2b.xy, w2p[2][1].xy); pk_fma(aA, r2b.zw, w2p[2][1].zw);
                    pk_fma(aB, r1a.xy, w2p[0][0].xy); pk_fma(aB, r1a.zw, w2p[0][0].zw);
                    pk_fma(aB, r1b.xy, w2p[0][1].xy); pk_fma(aB, r1b.zw, w2p[0][1].zw);
                    pk_fma(aB, r2a.xy, w2p[1][0].xy); pk_fma(aB, r2a.zw, w2p[1][0].zw);
                    pk_fma(aB, r2b.xy, w2p[1][1].xy); pk_fma(aB, r2b.zw, w2p[1][1].zw);
                    pk_fma(aB, r3a.xy, w2p[2][0].xy); pk_fma(aB, r3a.zw, w2p[2][0].zw);
                    pk_fma(aB, r3b.xy, w2p[2][1].xy); pk_fma(aB, r3b.zw, w2p[2][1].zw);
                    float sA = aA.x + aA.y, sB = aB.x + aB.y;
                    sA += __shfl_xor(sA, 32);
                    sB += __shfl_xor(sB, 32);
                    if (hf == 0)
                        seqb[ss][tl][co] = fmaxf(fmaxf(sA, sB) + b2v, 0.f);
                    r0a = r2a; r0b = r2b; r1a = r3a; r1b = r3b;
                    if (tl < CH - 1) {
                        r2a = pbase[(2 * tl + 4) * 4 + h2o]; r2b = pbase[(2 * tl + 4) * 4 + h2o + 1];
                        r3a = pbase[(2 * tl + 5) * 4 + h2o]; r3b = pbase[(2 * tl + 5) * 4 + h2o + 1];
                    }
                }
            }
        }
        __syncthreads();

        // ---- phase B': x-part of gates, both samples -> 32 registers ----
        float gpx0[SPB][CH], gpx1[SPB][CH];
        {
            const float* pwi = wih + (size_t)br * 4096 + (size_t)lane * 32;
            asm volatile("" : "+v"(pwi));
            v4f wiA[8], wiB[8];
            #pragma unroll
            for (int j = 0; j < 8; ++j) {
                wiA[j] = ((const v4f*)pwi)[j];
                wiB[j] = ((const v4f*)(pwi + 64 * 32))[j];
            }
            #pragma unroll
            for (int ss = 0; ss < SPB; ++ss) {
                #pragma unroll
                for (int tl = 0; tl < CH; ++tl) {
                    const v4f* xq = (const v4f*)&seqb[ss][tl][0];
                    v2f aA = {0.f, 0.f}, aB = {0.f, 0.f};
                    #pragma unroll
                    for (int j = 0; j < 8; ++j) {
                        v4f xv = xq[j];
                        pk_fma(aA, xv.xy, wiA[j].xy); pk_fma(aA, xv.zw, wiA[j].zw);
                        pk_fma(aB, xv.xy, wiB[j].xy); pk_fma(aB, xv.zw, wiB[j].zw);
                    }
                    gpx0[ss][tl] = aA.x + aA.y;
                    gpx1[ss][tl] = aB.x + aB.y;
                }
            }
        }

        // ---- phase C: h-part, both samples interleaved per step ----
        {
            const float* pwh = whh + (size_t)br * 4096 + (size_t)lane * 32;
            asm volatile("" : "+v"(pwh));
            v4f whA[8], whB[8];
            #pragma unroll
            for (int j = 0; j < 8; ++j) {
                whA[j] = ((const v4f*)pwh)[j];
                whB[j] = ((const v4f*)(pwh + 64 * 32))[j];
            }
            #pragma unroll
            for (int tl = 0; tl < CH; ++tl) {
                __syncthreads();
                const int p = tl & 1;          // tc0 even => parity = tl&1
                const v4f* hq0 = (const v4f*)&hb[p][0][0];
                const v4f* hq1 = (const v4f*)&hb[p][1][0];
                v2f aA0 = {0.f, 0.f}, aB0 = {0.f, 0.f};
                v2f aA1 = {0.f, 0.f}, aB1 = {0.f, 0.f};
                #pragma unroll
                for (int j = 0; j < 8; ++j) {
                    v4f h0 = hq0[j];
                    v4f h1 = hq1[j];
                    pk_fma(aA0, h0.xy, whA[j].xy); pk_fma(aA0, h0.zw, whA[j].zw);
                    pk_fma(aB0, h0.xy, whB[j].xy); pk_fma(aB0, h0.zw, whB[j].zw);
                    pk_fma(aA1, h1.xy, whA[j].xy); pk_fma(aA1, h1.zw, whA[j].zw);
                    pk_fma(aB1, h1.xy, whB[j].xy); pk_fma(aB1, h1.zw, whB[j].zw);
                }
                // sample 0
                float g00 = bs0 + gpx0[0][tl] + aA0.x + aA0.y;
                float g10 = bs1 + gpx1[0][tl] + aB0.x + aB0.y;
                // sample 1
                float g01 = bs0 + gpx0[1][tl] + aA1.x + aA1.y;
                float g11 = bs1 + gpx1[1][tl] + aB1.x + aB1.y;

                float a00 = sigf(g00);
                float a01 = sigf(g01);
                float e0 = __expf(fminf((lane < 32) ? 2.f * g10 : -g10, 80.f));
                float e1 = __expf(fminf((lane < 32) ? 2.f * g11 : -g11, 80.f));
                float n0 = (lane < 32) ? e0 - 1.f : 1.f;
                float n1 = (lane < 32) ? e1 - 1.f : 1.f;
                float a10 = __fdividef(n0, e0 + 1.f);
                float a11 = __fdividef(n1, e1 + 1.f);
                float fa0 = __shfl_xor(a00, 32);
                float fa1 = __shfl_xor(a01, 32);
                float oa0 = __shfl_xor(a10, 32);
                float oa1 = __shfl_xor(a11, 32);
                if (lane < 32) {
                    cst0 = fmaf(fa0, cst0, a00 * a10);
                    cst1 = fmaf(fa1, cst1, a01 * a11);
                    hb[p ^ 1][0][lane] = oa0 * tanhfast(cst0);
                    hb[p ^ 1][1][lane] = oa1 * tanhfast(cst1);
                }
            }
        }
    }

    __syncthreads();
    // last step (t=511) wrote parity (7&1)^1 = 0
    feats[((size_t)br * BATCH + s0 + (lane >> 5)) * 32 + (lane & 31)] =
        hb[0][lane >> 5][lane & 31];
}

// ---------------- tail: bottleneck + 8-qubit statevector + classifier -------

__device__ __forceinline__ void apply1q(float2* psi, int lane, int q,
                                        float2 g00, float2 g01,
                                        float2 g10, float2 g11)
{
    const int shift = 7 - q;
    const int right = 1 << shift;
    #pragma unroll
    for (int pp = 0; pp < 2; ++pp) {
        int p  = lane + 64 * pp;
        int l  = p >> shift;
        int r  = p & (right - 1);
        int i0 = (l << (shift + 1)) + r;
        int i1 = i0 + right;
        float2 a = psi[i0], b = psi[i1];
        float2 n0 = make_float2(g00.x * a.x - g00.y * a.y + g01.x * b.x - g01.y * b.y,
                                g00.x * a.y + g00.y * a.x + g01.x * b.y + g01.y * b.x);
        float2 n1 = make_float2(g10.x * a.x - g10.y * a.y + g11.x * b.x - g11.y * b.y,
                                g10.x * a.y + g10.y * a.x + g11.x * b.y + g11.y * b.x);
        psi[i0] = n0;
        psi[i1] = n1;
    }
    __syncthreads();
}

__global__ __launch_bounds__(64) void tail_kernel(
    const float* __restrict__ feats, const float* __restrict__ bw,
    const float* __restrict__ bb, const float* __restrict__ qw,
    const float* __restrict__ cw, const float* __restrict__ cb,
    float* __restrict__ out)
{
    const int s    = blockIdx.x;
    const int lane = threadIdx.x;

    __shared__ float comb[128];
    __shared__ float2 psi[256];
    __shared__ float ang[8];

    comb[lane]      = feats[(size_t)(lane >> 5) * (BATCH * 32) + (size_t)s * 32 + (lane & 31)];
    comb[lane + 64] = feats[(size_t)((lane + 64) >> 5) * (BATCH * 32) + (size_t)s * 32 + (lane & 31)];
    __syncthreads();

    {
        int q = lane >> 3, k0 = lane & 7;
        float p = 0.f;
        #pragma unroll
        for (int i = 0; i < 16; ++i) {
            int k = k0 + 8 * i;
            p = fmaf(comb[k], bw[q * 128 + k], p);
        }
        p += __shfl_xor(p, 4);
        p += __shfl_xor(p, 2);
        p += __shfl_xor(p, 1);
        if (k0 == 0) ang[q] = tanhf(p + bb[q]);
    }
    #pragma unroll
    for (int r = 0; r < 4; ++r) {
        int idx = lane + 64 * r;
        psi[idx] = make_float2(idx == 0 ? 1.f : 0.f, 0.f);
    }
    __syncthreads();

    const float PI_F = 3.14159265358979323846f;

    for (int q = 0; q < 8; ++q) {
        float half = ang[q] * PI_F * 0.5f;
        float cv = cosf(half), sv = sinf(half);
        apply1q(psi, lane, q,
                make_float2(cv, 0.f), make_float2(0.f, -sv),
                make_float2(0.f, -sv), make_float2(cv, 0.f));
    }

    for (int l = 0; l < 3; ++l) {
        for (int q = 0; q < 8; ++q) {
            float phi = qw[(l * 8 + q) * 3 + 0];
            float th  = qw[(l * 8 + q) * 3 + 1];
            float om  = qw[(l * 8 + q) * 3 + 2];
            float ct = cosf(0.5f * th), st = sinf(0.5f * th);
            float A = 0.5f * (phi + om), D = 0.5f * (phi - om);
            float cA = cosf(A), sA = sinf(A), cD = cosf(D), sD = sinf(D);
            apply1q(psi, lane, q,
                    make_float2(ct * cA, -ct * sA), make_float2(-st * cD, -st * sD),
                    make_float2(st * cD, -st * sD), make_float2(ct * cA,  ct * sA));
        }
        int stride = l + 1;
        for (int q = 0; q + stride < 8; ++q) {
            int cbit = 1 << (7 - q);
            int tbit = 1 << (7 - (q + stride));
            #pragma unroll
            for (int r = 0; r < 4; ++r) {
                int idx = lane + 64 * r;
                if ((idx & cbit) && !(idx & tbit)) {
                    int j = idx | tbit;
                    float2 tmp = psi[idx];
                    psi[idx] = psi[j];
                    psi[j] = tmp;
                }
            }
            __syncthreads();
        }
    }

    float z[8];
    #pragma unroll
    for (int q = 0; q < 8; ++q) z[q] = 0.f;
    #pragma unroll
    for (int r = 0; r < 4; ++r) {
        int idx = lane + 64 * r;
        float2 a = psi[idx];
        float pr = a.x * a.x + a.y * a.y;
        #pragma unroll
        for (int q = 0; q < 8; ++q)
            z[q] += (idx & (1 << (7 - q))) ? -pr : pr;
    }
    #pragma unroll
    for (int q = 0; q < 8; ++q) {
        #pragma unroll
        for (int off = 32; off; off >>= 1) z[q] += __shfl_xor(z[q], off);
    }
    if (lane == 0) {
        #pragma unroll
        for (int c = 0; c < 3; ++c) {
            float acc = cb[c];
            #pragma unroll
            for (int q = 0; q < 8; ++q) acc = fmaf(z[q], cw[c * 8 + q], acc);
            out[s * 3 + c] = acc;
        }
    }
}

extern "C" void kernel_launch(void* const* d_in, const int* in_sizes, int n_in,
                              void* d_out, int out_size, void* d_ws, size_t ws_size,
                              hipStream_t stream)
{
    (void)in_sizes; (void)n_in; (void)out_size; (void)ws_size;
    const float* x0  = (const float*)d_in[0];
    const float* x1  = (const float*)d_in[1];
    const float* x2  = (const float*)d_in[2];
    const float* x3  = (const float*)d_in[3];
    const float* c1w = (const float*)d_in[4];
    const float* c1b = (const float*)d_in[5];
    const float* c2w = (const float*)d_in[6];
    const float* c2b = (const float*)d_in[7];
    const float* wih = (const float*)d_in[8];
    const float* whh = (const float*)d_in[9];
    const float* bih = (const float*)d_in[10];
    const float* bhh = (const float*)d_in[11];
    const float* bw  = (const float*)d_in[12];
    const float* bb  = (const float*)d_in[13];
    const float* qw  = (const float*)d_in[14];
    const float* cw  = (const float*)d_in[15];
    const float* cb  = (const float*)d_in[16];

    float* feats = (float*)d_ws;  // [4][BATCH][32] f32 = 1 MB

    branch_kernel<<<dim3(BATCH / SPB, 4), 64, 0, stream>>>(
        x0, x1, x2, x3, c1w, c1b, c2w, c2b, wih, whh, bih, bhh, feats);
    tail_kernel<<<BATCH, 64, 0, stream>>>(
        feats, bw, bb, qw, cw, cb, (float*)d_out);
}